// Round 17
// baseline (460.198 us; speedup 1.0000x reference)
//
#include <hip/hip_runtime.h>

typedef __attribute__((ext_vector_type(8))) short short8;
typedef __attribute__((ext_vector_type(4))) float f32x4;
typedef __attribute__((ext_vector_type(4))) unsigned uint4v;

#define AST 168   // LDS tile stride in shorts (rows of 160 + pad; 336B = 21*16B)

// ---------------- bf16 helpers ----------------
__device__ inline unsigned f2bf(float f) {
    unsigned u = __float_as_uint(f);
    u += 0x7fffu + ((u >> 16) & 1u);   // round-to-nearest-even
    return u >> 16;
}
__device__ inline float bf2f(ushort h) { return __uint_as_float(((unsigned)h) << 16); }

__device__ inline void acc8(float* a, uint4v v) {
    a[0] += bf2f((ushort)(v.x & 0xffffu)); a[1] += bf2f((ushort)(v.x >> 16));
    a[2] += bf2f((ushort)(v.y & 0xffffu)); a[3] += bf2f((ushort)(v.y >> 16));
    a[4] += bf2f((ushort)(v.z & 0xffffu)); a[5] += bf2f((ushort)(v.z >> 16));
    a[6] += bf2f((ushort)(v.w & 0xffffu)); a[7] += bf2f((ushort)(v.w >> 16));
}

// ---------------- CSR build (bucketed) + fused x->bf16 convert ----------------
__global__ __launch_bounds__(256) void k_bcnt_cvt(const int* __restrict__ ei, int* __restrict__ bucket_cnt, int E,
                                                  const float* __restrict__ x, ushort* __restrict__ xb,
                                                  int total4, int bcb) {
    int tid = threadIdx.x;
    if (blockIdx.x < bcb) {
        __shared__ int hist[256];
        hist[tid] = 0;
        __syncthreads();
        int e0 = blockIdx.x * 4096;
#pragma unroll
        for (int k = 0; k < 16; ++k) {
            int e = e0 + k * 256 + tid;
            if (e < E) atomicAdd(&hist[ei[E + e] >> 9], 1);
        }
        __syncthreads();
        if (hist[tid]) atomicAdd(&bucket_cnt[tid], hist[tid]);
    } else {
        int i = (blockIdx.x - bcb) * 256 + tid;
        if (i >= total4) return;
        float4 v = ((const float4*)x)[i];
        unsigned lo = f2bf(v.x) | (f2bf(v.y) << 16);
        unsigned hi = f2bf(v.z) | (f2bf(v.w) << 16);
        ((uint2*)xb)[i] = make_uint2(lo, hi);
    }
}

// Merged small kernel: block 0 -> bucket scan; blocks 1..nbb -> graph bounds;
// blocks nbb+1.. -> extended weight conversion.
__global__ __launch_bounds__(256) void k_misc(const int* __restrict__ bucket_cnt, int* __restrict__ bucket_base,
                                              int* __restrict__ bucket_head, int* __restrict__ row_ptr,
                                              const int* __restrict__ batch, int* __restrict__ gstart,
                                              const float* __restrict__ W0, const float* __restrict__ b0,
                                              const float* __restrict__ W1, const float* __restrict__ b1,
                                              const float* __restrict__ W2, const float* __restrict__ b2,
                                              ushort* __restrict__ Wte,
                                              int n, int E, int nbuck, int G, int nbb) {
    int bid = blockIdx.x;
    int tid = threadIdx.x;
    if (bid == 0) {
        __shared__ int sdata[256];
        int t = (tid < nbuck) ? bucket_cnt[tid] : 0;
        int x = t;
        sdata[tid] = x; __syncthreads();
        for (int off = 1; off < 256; off <<= 1) {
            int y = (tid >= off) ? sdata[tid - off] : 0;
            __syncthreads();
            x += y; sdata[tid] = x; __syncthreads();
        }
        int excl = x - t;
        if (tid < nbuck) { bucket_base[tid] = excl; bucket_head[tid] = excl; }
        if (tid == nbuck - 1) bucket_base[nbuck] = excl + t;   // == E
        if (tid == 0) row_ptr[n] = E;
    } else if (bid <= nbb) {
        int i = (bid - 1) * 256 + tid;
        if (i >= n) return;
        int g = batch[i];
        if (i == 0) {
            for (int q = 0; q <= g; ++q) gstart[q] = 0;
        } else {
            int gp = batch[i - 1];
            for (int q = gp + 1; q <= g; ++q) gstart[q] = i;
        }
        if (i == n - 1) {
            for (int q = g + 1; q <= G; ++q) gstart[q] = n;
        }
    } else {
        int i = (bid - 1 - nbb) * 256 + tid;
        if (i >= 3 * 20480) return;
        int l = i / 20480, r = i % 20480;
        int nn = r / 160, kk = r % 160;
        const float* W = (l == 0) ? W0 : ((l == 1) ? W1 : W2);
        const float* b = (l == 0) ? b0 : ((l == 1) ? b1 : b2);
        float v = (kk < 132) ? W[kk * 128 + nn] : ((kk == 132) ? b[nn] : 0.f);
        Wte[(size_t)l * 20480 + nn * 160 + kk] = (ushort)f2bf(v);
    }
}

// Pass A: bin edges by dst bucket (8192-edge chunks). tmpA = src | (dst&511)<<17,
// tmpE = edge_attr as bf16x4 (contiguous e-ordered read of ea).
__global__ __launch_bounds__(256) void k_binA(const int* __restrict__ ei, const float* __restrict__ ea,
                                              int* __restrict__ bucket_head,
                                              int* __restrict__ tmpA, uint2* __restrict__ tmpE, int E) {
    __shared__ int hist[256], base[256], fill[256];
    int tid = threadIdx.x;
    hist[tid] = 0; fill[tid] = 0;
    __syncthreads();
    int e0 = blockIdx.x * 8192;
    int d[32];
#pragma unroll
    for (int k = 0; k < 32; ++k) {
        int e = e0 + k * 256 + tid;
        d[k] = -1;
        if (e < E) { d[k] = ei[E + e]; atomicAdd(&hist[d[k] >> 9], 1); }
    }
    __syncthreads();
    if (hist[tid]) base[tid] = atomicAdd(&bucket_head[tid], hist[tid]);
    __syncthreads();
#pragma unroll
    for (int k = 0; k < 32; ++k) {
        if (d[k] >= 0) {
            int e = e0 + k * 256 + tid;
            int b = d[k] >> 9;
            int p = base[b] + atomicAdd(&fill[b], 1);
            float4 a = ((const float4*)ea)[e];
            tmpA[p] = ei[e] | ((d[k] & 511) << 17);
            tmpE[p] = make_uint2(f2bf(a.x) | (f2bf(a.y) << 16), f2bf(a.z) | (f2bf(a.w) << 16));
        }
    }
}

// Pass B: one block per bucket. Builds row_ptr, scatters csr_src in a small window,
// accumulates agg_e in LDS fp32.
__global__ __launch_bounds__(256) void k_binB(const int* __restrict__ tmpA, const uint2* __restrict__ tmpE,
                                              const int* __restrict__ bucket_base, int* __restrict__ row_ptr,
                                              int* __restrict__ csr_src, float* __restrict__ agg_e, int n, int E) {
    __shared__ int lcnt[512];
    __shared__ int sscan[256];
    __shared__ float eacc[2048];
    int b = blockIdx.x;
    int lo = b << 9;
    int hi = lo + 512; if (hi > n) hi = n;
    int nn = hi - lo;
    int tid = threadIdx.x;
    lcnt[tid] = 0; lcnt[tid + 256] = 0;
#pragma unroll
    for (int i = 0; i < 8; ++i) eacc[tid + i * 256] = 0.f;
    __syncthreads();
    int jlo = bucket_base[b];
    int jhi = bucket_base[b + 1];
    for (int j = jlo + tid; j < jhi; j += 256) {
        atomicAdd(&lcnt[tmpA[j] >> 17], 1);
    }
    __syncthreads();
    int c0 = lcnt[2 * tid], c1 = lcnt[2 * tid + 1];
    int pair = c0 + c1;
    int x = pair;
    sscan[tid] = x; __syncthreads();
    for (int off = 1; off < 256; off <<= 1) {
        int y = (tid >= off) ? sscan[tid - off] : 0;
        __syncthreads();
        x += y; sscan[tid] = x; __syncthreads();
    }
    int h0 = jlo + (x - pair);
    int h1 = h0 + c0;
    __syncthreads();
    lcnt[2 * tid] = h0; lcnt[2 * tid + 1] = h1;
    if (2 * tid < nn)     row_ptr[lo + 2 * tid] = h0;
    if (2 * tid + 1 < nn) row_ptr[lo + 2 * tid + 1] = h1;
    __syncthreads();
    for (int j = jlo + tid; j < jhi; j += 256) {
        int w = tmpA[j];
        uint2 eav = tmpE[j];
        int d = w >> 17;
        int pos = atomicAdd(&lcnt[d], 1);
        csr_src[pos] = w & 0x1FFFF;
        atomicAdd(&eacc[d * 4 + 0], bf2f((ushort)(eav.x & 0xffffu)));
        atomicAdd(&eacc[d * 4 + 1], bf2f((ushort)(eav.x >> 16)));
        atomicAdd(&eacc[d * 4 + 2], bf2f((ushort)(eav.y & 0xffffu)));
        atomicAdd(&eacc[d * 4 + 3], bf2f((ushort)(eav.y >> 16)));
    }
    __syncthreads();
    for (int i = tid; i < nn * 4; i += 256) agg_e[lo * 4 + i] = eacc[i];
}

// ---------------- fused per-layer: 2 waves/block, each an independent 16-node tile ----
// 128-thread blocks, grid n/32, ZERO barriers (same-wave LDS ordering is HW-
// guaranteed). Residency: wg-cap 16/CU x 2 waves (vs r16's 1-wave 50% cap).
// Per wave: gather 16 rows -> private LDS tile -> 40 MFMA (K=160, bias+edge
// folded) -> direct register stores / pool-reduce.
__global__ __launch_bounds__(128) void k_fused(const ushort* __restrict__ xin, ushort* __restrict__ xout,
                                               const float* __restrict__ agg_e, const ushort* __restrict__ Wte,
                                               const int* __restrict__ row_ptr, const int* __restrict__ csr_src,
                                               const int* __restrict__ bat, float* __restrict__ pooled,
                                               int do_pool, int n) {
    __shared__ ushort atile2[2][16 * AST];
    int tid = threadIdx.x;
    int wave = tid >> 6, lane = tid & 63;
    int g = lane >> 4, t = lane & 15;
    int tile0 = blockIdx.x * 32 + wave * 16;
    ushort* atile = atile2[wave];

    const uint4v* x4 = (const uint4v*)xin;

    // ---- gather 16 nodes (wave-local, no barriers) ----
    for (int q = 0; q < 16; ++q) {
        int v = tile0 + q;
        float acc[8] = {0.f, 0.f, 0.f, 0.f, 0.f, 0.f, 0.f, 0.f};
        if (v < n) {
            if (g == 0) acc8(acc, x4[(size_t)v * 16 + t]);   // self loop
            int start = row_ptr[v];
            int deg = row_ptr[v + 1] - start;
            int i = g;
            for (; i + 12 < deg; i += 16) {
                int s0 = csr_src[start + i];
                int s1 = csr_src[start + i + 4];
                int s2 = csr_src[start + i + 8];
                int s3 = csr_src[start + i + 12];
                uint4v v0 = x4[(size_t)s0 * 16 + t];
                uint4v v1 = x4[(size_t)s1 * 16 + t];
                uint4v v2 = x4[(size_t)s2 * 16 + t];
                uint4v v3 = x4[(size_t)s3 * 16 + t];
                acc8(acc, v0); acc8(acc, v1); acc8(acc, v2); acc8(acc, v3);
            }
            for (; i + 4 < deg; i += 8) {
                int s0 = csr_src[start + i];
                int s1 = csr_src[start + i + 4];
                uint4v v0 = x4[(size_t)s0 * 16 + t];
                uint4v v1 = x4[(size_t)s1 * 16 + t];
                acc8(acc, v0); acc8(acc, v1);
            }
            if (i < deg) {
                int s0 = csr_src[start + i];
                acc8(acc, x4[(size_t)s0 * 16 + t]);
            }
        }
#pragma unroll
        for (int j = 0; j < 8; ++j) {
            acc[j] += __shfl_xor(acc[j], 16);
            acc[j] += __shfl_xor(acc[j], 32);
        }
        if (lane < 16) {
            uint4v o;
            o.x = f2bf(acc[0]) | (f2bf(acc[1]) << 16);
            o.y = f2bf(acc[2]) | (f2bf(acc[3]) << 16);
            o.z = f2bf(acc[4]) | (f2bf(acc[5]) << 16);
            o.w = f2bf(acc[6]) | (f2bf(acc[7]) << 16);
            *(uint4v*)&atile[q * AST + lane * 8] = o;
        } else if (lane < 20) {
            // K-extension: agg_e (bf16 x4), 1.0 at k=132, zeros to k=159
            uint4v o = {0u, 0u, 0u, 0u};
            if (lane == 16) {
                float4 e = make_float4(0.f, 0.f, 0.f, 0.f);
                if (v < n) e = *(const float4*)(agg_e + (size_t)v * 4);
                o.x = f2bf(e.x) | (f2bf(e.y) << 16);
                o.y = f2bf(e.z) | (f2bf(e.w) << 16);
                o.z = 0x3f80u;   // bf16(1.0) at k=132, k=133 zero
            }
            *(uint4v*)&atile[q * AST + 128 + (lane - 16) * 8] = o;
        }
    }

    // ---- MFMA over K=160, all 8 N-chains in this wave ----
    int r16 = lane & 15;
    int kc = (lane >> 4) * 8;
    short8 a0 = *(const short8*)&atile[r16 * AST +   0 + kc];
    short8 a1 = *(const short8*)&atile[r16 * AST +  32 + kc];
    short8 a2 = *(const short8*)&atile[r16 * AST +  64 + kc];
    short8 a3 = *(const short8*)&atile[r16 * AST +  96 + kc];
    short8 a4 = *(const short8*)&atile[r16 * AST + 128 + kc];
    f32x4 oc[8];
#pragma unroll
    for (int nt = 0; nt < 8; ++nt) {
        const ushort* wb = Wte + (size_t)(nt * 16 + r16) * 160 + kc;
        f32x4 a = (f32x4){0.f, 0.f, 0.f, 0.f};
        a = __builtin_amdgcn_mfma_f32_16x16x32_bf16(a0, *(const short8*)(wb +   0), a, 0, 0, 0);
        a = __builtin_amdgcn_mfma_f32_16x16x32_bf16(a1, *(const short8*)(wb +  32), a, 0, 0, 0);
        a = __builtin_amdgcn_mfma_f32_16x16x32_bf16(a2, *(const short8*)(wb +  64), a, 0, 0, 0);
        a = __builtin_amdgcn_mfma_f32_16x16x32_bf16(a3, *(const short8*)(wb +  96), a, 0, 0, 0);
        a = __builtin_amdgcn_mfma_f32_16x16x32_bf16(a4, *(const short8*)(wb + 128), a, 0, 0, 0);
        oc[nt] = a;
    }

    if (do_pool) {
        // ---- layer-3: no store; per-graph reduce of relu'd acc -> pooled ----
        int lastrow = tile0 + 15; if (lastrow >= n) lastrow = n - 1;
        int g_first = bat[tile0 < n ? tile0 : (n - 1)];
        int g_last = bat[lastrow];
        for (int gg = g_first; gg <= g_last; ++gg) {
            float s[8] = {0.f, 0.f, 0.f, 0.f, 0.f, 0.f, 0.f, 0.f};
#pragma unroll
            for (int r = 0; r < 4; ++r) {
                int grow = tile0 + (lane >> 4) * 4 + r;
                if (grow < n && bat[grow] == gg) {
#pragma unroll
                    for (int nt = 0; nt < 8; ++nt) s[nt] += fmaxf(oc[nt][r], 0.f);
                }
            }
#pragma unroll
            for (int nt = 0; nt < 8; ++nt) {
                s[nt] += __shfl_xor(s[nt], 16);
                s[nt] += __shfl_xor(s[nt], 32);
            }
            if (lane < 16) {
#pragma unroll
                for (int nt = 0; nt < 8; ++nt)
                    atomicAdd(&pooled[gg * 128 + nt * 16 + r16], s[nt]);
            }
        }
    } else {
        // ---- direct register stores (16 consecutive ushorts per nt-segment) ----
#pragma unroll
        for (int r = 0; r < 4; ++r) {
            int grow = tile0 + (lane >> 4) * 4 + r;
            if (grow < n) {
#pragma unroll
                for (int nt = 0; nt < 8; ++nt)
                    xout[(size_t)grow * 128 + nt * 16 + r16] = (ushort)f2bf(fmaxf(oc[nt][r], 0.f));
            }
        }
    }
}

__global__ __launch_bounds__(128) void k_final(const float* __restrict__ pooled, const int* __restrict__ gstart,
                                               const float* __restrict__ Wout, const float* __restrict__ bout,
                                               float* __restrict__ out, int G) {
    int g = threadIdx.x;
    if (g >= G) return;
    float c = (float)(gstart[g + 1] - gstart[g]);
    if (c < 1.f) c = 1.f;
    float l0 = bout[0], l1 = bout[1], l2 = bout[2], l3 = bout[3];
    for (int k = 0; k < 128; ++k) {
        float p = pooled[g * 128 + k] / c;
        l0 += p * Wout[k * 4 + 0];
        l1 += p * Wout[k * 4 + 1];
        l2 += p * Wout[k * 4 + 2];
        l3 += p * Wout[k * 4 + 3];
    }
    float m = fmaxf(fmaxf(l0, l1), fmaxf(l2, l3));
    float s = expf(l0 - m) + expf(l1 - m) + expf(l2 - m) + expf(l3 - m);
    float ls = logf(s);
    out[g * 4 + 0] = l0 - m - ls;
    out[g * 4 + 1] = l1 - m - ls;
    out[g * 4 + 2] = l2 - m - ls;
    out[g * 4 + 3] = l3 - m - ls;
}

extern "C" void kernel_launch(void* const* d_in, const int* in_sizes, int n_in,
                              void* d_out, int out_size, void* d_ws, size_t ws_size,
                              hipStream_t stream) {
    const float* x    = (const float*)d_in[0];
    const int*   ei   = (const int*)d_in[1];
    const float* ea   = (const float*)d_in[2];
    const int*   bat  = (const int*)d_in[3];
    const float* W0   = (const float*)d_in[4];
    const float* b0   = (const float*)d_in[5];
    const float* W1   = (const float*)d_in[6];
    const float* b1   = (const float*)d_in[7];
    const float* W2   = (const float*)d_in[8];
    const float* b2   = (const float*)d_in[9];
    const float* Wout = (const float*)d_in[10];
    const float* bout = (const float*)d_in[11];
    float* out = (float*)d_out;

    int n = in_sizes[0] / 128;   // n < 2^17 assumed by tmpA packing (n = 100000 here)
    int E = in_sizes[1] / 2;
    int G = out_size / 4;
    int nbuck = (n + 511) >> 9;   // 196 for n=100000 (max 256 supported)
    int nbb = (n + 255) / 256;    // bounds blocks

    char* w = (char*)d_ws;
    auto alloc = [&](size_t bytes) { char* p = w; w += (bytes + 255) & ~(size_t)255; return p; };
    int* row_ptr     = (int*)alloc((size_t)(n + 1) * 4);
    int* bucket_cnt  = (int*)alloc(1024);
    int* bucket_base = (int*)alloc(1028);
    int* bucket_head = (int*)alloc(1024);
    int* csr_src     = (int*)alloc((size_t)E * 4);
    int* tmpA        = (int*)alloc((size_t)E * 4);
    uint2* tmpE      = (uint2*)alloc((size_t)E * 8);
    float* agg_e     = (float*)alloc((size_t)n * 16);
    float* pooled    = (float*)alloc((size_t)G * 128 * 4);
    int* gstart      = (int*)alloc((size_t)(G + 4) * 4);
    ushort* xb       = (ushort*)alloc((size_t)n * 128 * 2);
    ushort* yb       = (ushort*)alloc((size_t)n * 128 * 2);
    ushort* Wte      = (ushort*)alloc(3 * 20480 * 2);

    hipMemsetAsync(bucket_cnt, 0, 1024, stream);
    hipMemsetAsync(pooled, 0, (size_t)G * 128 * 4, stream);

    int bcb = (E + 4095) / 4096;           // bcnt blocks
    int cvb = (n * 32 + 255) / 256;        // cvt blocks
    int eb32 = (E + 8191) / 8192;
    k_bcnt_cvt<<<bcb + cvb, 256, 0, stream>>>(ei, bucket_cnt, E, x, xb, n * 32, bcb);
    k_misc<<<1 + nbb + 240, 256, 0, stream>>>(bucket_cnt, bucket_base, bucket_head, row_ptr,
                                              bat, gstart, W0, b0, W1, b1, W2, b2, Wte,
                                              n, E, nbuck, G, nbb);
    k_binA<<<eb32, 256, 0, stream>>>(ei, ea, bucket_head, tmpA, tmpE, E);
    k_binB<<<nbuck, 256, 0, stream>>>(tmpA, tmpE, bucket_base, row_ptr, csr_src, agg_e, n, E);

    int fb = (n + 31) / 32;   // 2 waves/block, each wave an independent 16-node tile

    k_fused<<<fb, 128, 0, stream>>>(xb, yb, agg_e, Wte +     0, row_ptr, csr_src, bat, pooled, 0, n);
    k_fused<<<fb, 128, 0, stream>>>(yb, xb, agg_e, Wte + 20480, row_ptr, csr_src, bat, pooled, 0, n);
    k_fused<<<fb, 128, 0, stream>>>(xb, yb, agg_e, Wte + 40960, row_ptr, csr_src, bat, pooled, 1, n);

    k_final<<<1, 128, 0, stream>>>(pooled, gstart, Wout, bout, out, G);
}

// Round 18
// 353.200 us; speedup vs baseline: 1.3029x; 1.3029x over previous
//
#include <hip/hip_runtime.h>

typedef __attribute__((ext_vector_type(8))) short short8;
typedef __attribute__((ext_vector_type(4))) float f32x4;
typedef __attribute__((ext_vector_type(4))) unsigned uint4v;

#define AST 168     // LDS tile stride in shorts (rows of 160 + pad; 336B = 21*16B)
#define TCAP 10240  // fixed per-bucket tmp capacity (mean 8192, std ~90 -> 25 sigma)

// ---------------- bf16 helpers ----------------
__device__ inline unsigned f2bf(float f) {
    unsigned u = __float_as_uint(f);
    u += 0x7fffu + ((u >> 16) & 1u);   // round-to-nearest-even
    return u >> 16;
}
__device__ inline float bf2f(ushort h) { return __uint_as_float(((unsigned)h) << 16); }

__device__ inline void acc8(float* a, uint4v v) {
    a[0] += bf2f((ushort)(v.x & 0xffffu)); a[1] += bf2f((ushort)(v.x >> 16));
    a[2] += bf2f((ushort)(v.y & 0xffffu)); a[3] += bf2f((ushort)(v.y >> 16));
    a[4] += bf2f((ushort)(v.z & 0xffffu)); a[5] += bf2f((ushort)(v.z >> 16));
    a[6] += bf2f((ushort)(v.w & 0xffffu)); a[7] += bf2f((ushort)(v.w >> 16));
}

// ---------------- Pass A (fixed-capacity regions) + fused x->bf16 convert ----------
// Blocks [0, ebA): bin edges into tmp[b*TCAP ...] via per-bucket fill counters
// (LDS-aggregated reservation). Leaves bucket_fill[b] = per-bucket totals.
// Blocks [ebA, ...): x -> xb bf16 convert.
__global__ __launch_bounds__(256) void k_binA_cvt(const int* __restrict__ ei, const float* __restrict__ ea,
                                                  int* __restrict__ bucket_fill,
                                                  int* __restrict__ tmpA, uint2* __restrict__ tmpE, int E,
                                                  const float* __restrict__ x, ushort* __restrict__ xb,
                                                  int total4, int ebA) {
    int tid = threadIdx.x;
    if (blockIdx.x >= ebA) {
        int i = (blockIdx.x - ebA) * 256 + tid;
        if (i >= total4) return;
        float4 v = ((const float4*)x)[i];
        unsigned lo = f2bf(v.x) | (f2bf(v.y) << 16);
        unsigned hi = f2bf(v.z) | (f2bf(v.w) << 16);
        ((uint2*)xb)[i] = make_uint2(lo, hi);
        return;
    }
    __shared__ int hist[256], base[256], fill[256];
    hist[tid] = 0; fill[tid] = 0;
    __syncthreads();
    int e0 = blockIdx.x * 8192;
    int d[32];
#pragma unroll
    for (int k = 0; k < 32; ++k) {
        int e = e0 + k * 256 + tid;
        d[k] = -1;
        if (e < E) { d[k] = ei[E + e]; atomicAdd(&hist[d[k] >> 9], 1); }
    }
    __syncthreads();
    if (hist[tid]) base[tid] = atomicAdd(&bucket_fill[tid], hist[tid]);
    __syncthreads();
#pragma unroll
    for (int k = 0; k < 32; ++k) {
        if (d[k] >= 0) {
            int e = e0 + k * 256 + tid;
            int b = d[k] >> 9;
            size_t p = (size_t)b * TCAP + base[b] + atomicAdd(&fill[b], 1);
            float4 a = ((const float4*)ea)[e];
            tmpA[p] = ei[e] | ((d[k] & 511) << 17);
            tmpE[p] = make_uint2(f2bf(a.x) | (f2bf(a.y) << 16), f2bf(a.z) | (f2bf(a.w) << 16));
        }
    }
}

// Merged small kernel: block 0 -> scan of bucket_fill -> bucket_base;
// blocks 1..nbb -> graph bounds; blocks nbb+1.. -> extended weight conversion.
__global__ __launch_bounds__(256) void k_misc(const int* __restrict__ bucket_fill, int* __restrict__ bucket_base,
                                              int* __restrict__ row_ptr,
                                              const int* __restrict__ batch, int* __restrict__ gstart,
                                              const float* __restrict__ W0, const float* __restrict__ b0,
                                              const float* __restrict__ W1, const float* __restrict__ b1,
                                              const float* __restrict__ W2, const float* __restrict__ b2,
                                              ushort* __restrict__ Wte,
                                              int n, int E, int nbuck, int G, int nbb) {
    int bid = blockIdx.x;
    int tid = threadIdx.x;
    if (bid == 0) {
        __shared__ int sdata[256];
        int t = (tid < nbuck) ? bucket_fill[tid] : 0;
        int x = t;
        sdata[tid] = x; __syncthreads();
        for (int off = 1; off < 256; off <<= 1) {
            int y = (tid >= off) ? sdata[tid - off] : 0;
            __syncthreads();
            x += y; sdata[tid] = x; __syncthreads();
        }
        int excl = x - t;
        if (tid < nbuck) bucket_base[tid] = excl;
        if (tid == nbuck - 1) bucket_base[nbuck] = excl + t;   // == E
        if (tid == 0) row_ptr[n] = E;
    } else if (bid <= nbb) {
        int i = (bid - 1) * 256 + tid;
        if (i >= n) return;
        int g = batch[i];
        if (i == 0) {
            for (int q = 0; q <= g; ++q) gstart[q] = 0;
        } else {
            int gp = batch[i - 1];
            for (int q = gp + 1; q <= g; ++q) gstart[q] = i;
        }
        if (i == n - 1) {
            for (int q = g + 1; q <= G; ++q) gstart[q] = n;
        }
    } else {
        int i = (bid - 1 - nbb) * 256 + tid;
        if (i >= 3 * 20480) return;
        int l = i / 20480, r = i % 20480;
        int nn = r / 160, kk = r % 160;
        const float* W = (l == 0) ? W0 : ((l == 1) ? W1 : W2);
        const float* b = (l == 0) ? b0 : ((l == 1) ? b1 : b2);
        float v = (kk < 132) ? W[kk * 128 + nn] : ((kk == 132) ? b[nn] : 0.f);
        Wte[(size_t)l * 20480 + nn * 160 + kk] = (ushort)f2bf(v);
    }
}

// Pass B: one block per bucket (fixed tmp region). Builds row_ptr, scatters
// csr_src into the bucket's compact CSR window, accumulates agg_e in LDS fp32.
__global__ __launch_bounds__(256) void k_binB(const int* __restrict__ tmpA, const uint2* __restrict__ tmpE,
                                              const int* __restrict__ bucket_fill, const int* __restrict__ bucket_base,
                                              int* __restrict__ row_ptr, int* __restrict__ csr_src,
                                              float* __restrict__ agg_e, int n, int E) {
    __shared__ int lcnt[512];
    __shared__ int sscan[256];
    __shared__ float eacc[2048];
    int b = blockIdx.x;
    int lo = b << 9;
    int hi = lo + 512; if (hi > n) hi = n;
    int nn = hi - lo;
    int tid = threadIdx.x;
    lcnt[tid] = 0; lcnt[tid + 256] = 0;
#pragma unroll
    for (int i = 0; i < 8; ++i) eacc[tid + i * 256] = 0.f;
    __syncthreads();
    size_t jlo = (size_t)b * TCAP;
    int cnt = bucket_fill[b];
    int gbase = bucket_base[b];
    for (int j = tid; j < cnt; j += 256) {
        atomicAdd(&lcnt[tmpA[jlo + j] >> 17], 1);
    }
    __syncthreads();
    int c0 = lcnt[2 * tid], c1 = lcnt[2 * tid + 1];
    int pair = c0 + c1;
    int x = pair;
    sscan[tid] = x; __syncthreads();
    for (int off = 1; off < 256; off <<= 1) {
        int y = (tid >= off) ? sscan[tid - off] : 0;
        __syncthreads();
        x += y; sscan[tid] = x; __syncthreads();
    }
    int h0 = gbase + (x - pair);
    int h1 = h0 + c0;
    __syncthreads();
    lcnt[2 * tid] = h0; lcnt[2 * tid + 1] = h1;
    if (2 * tid < nn)     row_ptr[lo + 2 * tid] = h0;
    if (2 * tid + 1 < nn) row_ptr[lo + 2 * tid + 1] = h1;
    __syncthreads();
    for (int j = tid; j < cnt; j += 256) {
        int w = tmpA[jlo + j];
        uint2 eav = tmpE[jlo + j];
        int d = w >> 17;
        int pos = atomicAdd(&lcnt[d], 1);
        csr_src[pos] = w & 0x1FFFF;
        atomicAdd(&eacc[d * 4 + 0], bf2f((ushort)(eav.x & 0xffffu)));
        atomicAdd(&eacc[d * 4 + 1], bf2f((ushort)(eav.x >> 16)));
        atomicAdd(&eacc[d * 4 + 2], bf2f((ushort)(eav.y & 0xffffu)));
        atomicAdd(&eacc[d * 4 + 3], bf2f((ushort)(eav.y >> 16)));
    }
    __syncthreads();
    for (int i = tid; i < nn * 4; i += 256) agg_e[lo * 4 + i] = eacc[i];
}

// ---------------- fused per-layer (r15-proven): gather + MFMA(K=160) + relu [+pool] ----
// 16 nodes/block, 4 waves, ONE barrier. Phase 1: wave gathers 4 nodes (unroll x4).
// Phase 2: wave w computes nt={2w,2w+1} over 5 K-chains (bias+edge folded).
// Epilogue: direct register stores, or per-graph shfl-reduce + atomicAdd when do_pool.
__global__ __launch_bounds__(256) void k_fused(const ushort* __restrict__ xin, ushort* __restrict__ xout,
                                               const float* __restrict__ agg_e, const ushort* __restrict__ Wte,
                                               const int* __restrict__ row_ptr, const int* __restrict__ csr_src,
                                               const int* __restrict__ bat, float* __restrict__ pooled,
                                               int do_pool, int n) {
    __shared__ ushort atile[16 * AST];
    int tid = threadIdx.x;
    int wave = tid >> 6, lane = tid & 63;
    int g = lane >> 4, t = lane & 15;
    int tile0 = blockIdx.x * 16;

    const uint4v* x4 = (const uint4v*)xin;

    // ---- phase 1: gather 4 nodes per wave ----
    for (int q = 0; q < 4; ++q) {
        int v = tile0 + wave * 4 + q;      // wave-uniform
        float acc[8] = {0.f, 0.f, 0.f, 0.f, 0.f, 0.f, 0.f, 0.f};
        if (v < n) {
            if (g == 0) acc8(acc, x4[(size_t)v * 16 + t]);   // self loop
            int start = row_ptr[v];
            int deg = row_ptr[v + 1] - start;
            int i = g;
            for (; i + 12 < deg; i += 16) {
                int s0 = csr_src[start + i];
                int s1 = csr_src[start + i + 4];
                int s2 = csr_src[start + i + 8];
                int s3 = csr_src[start + i + 12];
                uint4v v0 = x4[(size_t)s0 * 16 + t];
                uint4v v1 = x4[(size_t)s1 * 16 + t];
                uint4v v2 = x4[(size_t)s2 * 16 + t];
                uint4v v3 = x4[(size_t)s3 * 16 + t];
                acc8(acc, v0); acc8(acc, v1); acc8(acc, v2); acc8(acc, v3);
            }
            for (; i + 4 < deg; i += 8) {
                int s0 = csr_src[start + i];
                int s1 = csr_src[start + i + 4];
                uint4v v0 = x4[(size_t)s0 * 16 + t];
                uint4v v1 = x4[(size_t)s1 * 16 + t];
                acc8(acc, v0); acc8(acc, v1);
            }
            if (i < deg) {
                int s0 = csr_src[start + i];
                acc8(acc, x4[(size_t)s0 * 16 + t]);
            }
        }
#pragma unroll
        for (int j = 0; j < 8; ++j) {
            acc[j] += __shfl_xor(acc[j], 16);
            acc[j] += __shfl_xor(acc[j], 32);
        }
        int rowi = wave * 4 + q;
        if (lane < 16) {
            uint4v o;
            o.x = f2bf(acc[0]) | (f2bf(acc[1]) << 16);
            o.y = f2bf(acc[2]) | (f2bf(acc[3]) << 16);
            o.z = f2bf(acc[4]) | (f2bf(acc[5]) << 16);
            o.w = f2bf(acc[6]) | (f2bf(acc[7]) << 16);
            *(uint4v*)&atile[rowi * AST + lane * 8] = o;
        } else if (lane < 20) {
            // K-extension: agg_e (bf16 x4), 1.0 at k=132, zeros to k=159
            uint4v o = {0u, 0u, 0u, 0u};
            if (lane == 16) {
                float4 e = make_float4(0.f, 0.f, 0.f, 0.f);
                if (v < n) e = *(const float4*)(agg_e + (size_t)v * 4);
                o.x = f2bf(e.x) | (f2bf(e.y) << 16);
                o.y = f2bf(e.z) | (f2bf(e.w) << 16);
                o.z = 0x3f80u;   // bf16(1.0) at k=132, k=133 zero
            }
            *(uint4v*)&atile[rowi * AST + 128 + (lane - 16) * 8] = o;
        }
    }
    __syncthreads();

    // ---- phase 2: MFMA over K=160, wave w owns nt = {2w, 2w+1} ----
    int r16 = lane & 15;
    int kc = (lane >> 4) * 8;
    short8 a0 = *(const short8*)&atile[r16 * AST +   0 + kc];
    short8 a1 = *(const short8*)&atile[r16 * AST +  32 + kc];
    short8 a2 = *(const short8*)&atile[r16 * AST +  64 + kc];
    short8 a3 = *(const short8*)&atile[r16 * AST +  96 + kc];
    short8 a4 = *(const short8*)&atile[r16 * AST + 128 + kc];
    const ushort* wb0 = Wte + (size_t)(wave * 32 + r16) * 160 + kc;
    const ushort* wb1 = wb0 + 16 * 160;
    f32x4 acc0 = (f32x4){0.f, 0.f, 0.f, 0.f};
    f32x4 acc1 = (f32x4){0.f, 0.f, 0.f, 0.f};
    acc0 = __builtin_amdgcn_mfma_f32_16x16x32_bf16(a0, *(const short8*)(wb0 +   0), acc0, 0, 0, 0);
    acc1 = __builtin_amdgcn_mfma_f32_16x16x32_bf16(a0, *(const short8*)(wb1 +   0), acc1, 0, 0, 0);
    acc0 = __builtin_amdgcn_mfma_f32_16x16x32_bf16(a1, *(const short8*)(wb0 +  32), acc0, 0, 0, 0);
    acc1 = __builtin_amdgcn_mfma_f32_16x16x32_bf16(a1, *(const short8*)(wb1 +  32), acc1, 0, 0, 0);
    acc0 = __builtin_amdgcn_mfma_f32_16x16x32_bf16(a2, *(const short8*)(wb0 +  64), acc0, 0, 0, 0);
    acc1 = __builtin_amdgcn_mfma_f32_16x16x32_bf16(a2, *(const short8*)(wb1 +  64), acc1, 0, 0, 0);
    acc0 = __builtin_amdgcn_mfma_f32_16x16x32_bf16(a3, *(const short8*)(wb0 +  96), acc0, 0, 0, 0);
    acc1 = __builtin_amdgcn_mfma_f32_16x16x32_bf16(a3, *(const short8*)(wb1 +  96), acc1, 0, 0, 0);
    acc0 = __builtin_amdgcn_mfma_f32_16x16x32_bf16(a4, *(const short8*)(wb0 + 128), acc0, 0, 0, 0);
    acc1 = __builtin_amdgcn_mfma_f32_16x16x32_bf16(a4, *(const short8*)(wb1 + 128), acc1, 0, 0, 0);

    if (do_pool) {
        // ---- layer-3: no store; per-graph reduce of relu'd acc -> pooled ----
        int lastrow = tile0 + 15; if (lastrow >= n) lastrow = n - 1;
        int g_first = bat[tile0];
        int g_last = bat[lastrow];
        int c0 = wave * 32 + r16;
        for (int gg = g_first; gg <= g_last; ++gg) {
            float s0 = 0.f, s1 = 0.f;
#pragma unroll
            for (int r = 0; r < 4; ++r) {
                int grow = tile0 + (lane >> 4) * 4 + r;
                if (grow < n && bat[grow] == gg) {
                    s0 += fmaxf(acc0[r], 0.f);
                    s1 += fmaxf(acc1[r], 0.f);
                }
            }
            s0 += __shfl_xor(s0, 16); s0 += __shfl_xor(s0, 32);
            s1 += __shfl_xor(s1, 16); s1 += __shfl_xor(s1, 32);
            if (lane < 16) {
                atomicAdd(&pooled[gg * 128 + c0], s0);
                atomicAdd(&pooled[gg * 128 + c0 + 16], s1);
            }
        }
    } else {
        // ---- direct register stores: lanes r16=0..15 -> consecutive ushorts (32B) ----
        int c0 = wave * 32 + r16;
#pragma unroll
        for (int r = 0; r < 4; ++r) {
            int grow = tile0 + (lane >> 4) * 4 + r;
            if (grow < n) {
                xout[(size_t)grow * 128 + c0]      = (ushort)f2bf(fmaxf(acc0[r], 0.f));
                xout[(size_t)grow * 128 + c0 + 16] = (ushort)f2bf(fmaxf(acc1[r], 0.f));
            }
        }
    }
}

__global__ __launch_bounds__(128) void k_final(const float* __restrict__ pooled, const int* __restrict__ gstart,
                                               const float* __restrict__ Wout, const float* __restrict__ bout,
                                               float* __restrict__ out, int G) {
    int g = threadIdx.x;
    if (g >= G) return;
    float c = (float)(gstart[g + 1] - gstart[g]);
    if (c < 1.f) c = 1.f;
    float l0 = bout[0], l1 = bout[1], l2 = bout[2], l3 = bout[3];
    for (int k = 0; k < 128; ++k) {
        float p = pooled[g * 128 + k] / c;
        l0 += p * Wout[k * 4 + 0];
        l1 += p * Wout[k * 4 + 1];
        l2 += p * Wout[k * 4 + 2];
        l3 += p * Wout[k * 4 + 3];
    }
    float m = fmaxf(fmaxf(l0, l1), fmaxf(l2, l3));
    float s = expf(l0 - m) + expf(l1 - m) + expf(l2 - m) + expf(l3 - m);
    float ls = logf(s);
    out[g * 4 + 0] = l0 - m - ls;
    out[g * 4 + 1] = l1 - m - ls;
    out[g * 4 + 2] = l2 - m - ls;
    out[g * 4 + 3] = l3 - m - ls;
}

extern "C" void kernel_launch(void* const* d_in, const int* in_sizes, int n_in,
                              void* d_out, int out_size, void* d_ws, size_t ws_size,
                              hipStream_t stream) {
    const float* x    = (const float*)d_in[0];
    const int*   ei   = (const int*)d_in[1];
    const float* ea   = (const float*)d_in[2];
    const int*   bat  = (const int*)d_in[3];
    const float* W0   = (const float*)d_in[4];
    const float* b0   = (const float*)d_in[5];
    const float* W1   = (const float*)d_in[6];
    const float* b1   = (const float*)d_in[7];
    const float* W2   = (const float*)d_in[8];
    const float* b2   = (const float*)d_in[9];
    const float* Wout = (const float*)d_in[10];
    const float* bout = (const float*)d_in[11];
    float* out = (float*)d_out;

    int n = in_sizes[0] / 128;   // n < 2^17 assumed by tmpA packing (n = 100000 here)
    int E = in_sizes[1] / 2;
    int G = out_size / 4;
    int nbuck = (n + 511) >> 9;   // 196 for n=100000 (max 256 supported)
    int nbb = (n + 255) / 256;    // bounds blocks

    char* w = (char*)d_ws;
    auto alloc = [&](size_t bytes) { char* p = w; w += (bytes + 255) & ~(size_t)255; return p; };
    int* row_ptr     = (int*)alloc((size_t)(n + 1) * 4);
    int* bucket_fill = (int*)alloc(1024);
    int* bucket_base = (int*)alloc(1028);
    int* csr_src     = (int*)alloc((size_t)E * 4);
    int* tmpA        = (int*)alloc((size_t)nbuck * TCAP * 4);
    uint2* tmpE      = (uint2*)alloc((size_t)nbuck * TCAP * 8);
    float* agg_e     = (float*)alloc((size_t)n * 16);
    float* pooled    = (float*)alloc((size_t)G * 128 * 4);
    int* gstart      = (int*)alloc((size_t)(G + 4) * 4);
    ushort* xb       = (ushort*)alloc((size_t)n * 128 * 2);
    ushort* yb       = (ushort*)alloc((size_t)n * 128 * 2);
    ushort* Wte      = (ushort*)alloc(3 * 20480 * 2);

    hipMemsetAsync(bucket_fill, 0, 1024, stream);
    hipMemsetAsync(pooled, 0, (size_t)G * 128 * 4, stream);

    int ebA = (E + 8191) / 8192;           // binA blocks
    int cvb = (n * 32 + 255) / 256;        // cvt blocks
    k_binA_cvt<<<ebA + cvb, 256, 0, stream>>>(ei, ea, bucket_fill, tmpA, tmpE, E, x, xb, n * 32, ebA);
    k_misc<<<1 + nbb + 240, 256, 0, stream>>>(bucket_fill, bucket_base, row_ptr,
                                              bat, gstart, W0, b0, W1, b1, W2, b2, Wte,
                                              n, E, nbuck, G, nbb);
    k_binB<<<nbuck, 256, 0, stream>>>(tmpA, tmpE, bucket_fill, bucket_base, row_ptr, csr_src, agg_e, n, E);

    int fb = (n + 15) / 16;   // 16 nodes per block (r15-proven grid)

    k_fused<<<fb, 256, 0, stream>>>(xb, yb, agg_e, Wte +     0, row_ptr, csr_src, bat, pooled, 0, n);
    k_fused<<<fb, 256, 0, stream>>>(yb, xb, agg_e, Wte + 20480, row_ptr, csr_src, bat, pooled, 0, n);
    k_fused<<<fb, 256, 0, stream>>>(xb, yb, agg_e, Wte + 40960, row_ptr, csr_src, bat, pooled, 1, n);

    k_final<<<1, 128, 0, stream>>>(pooled, gstart, Wout, bout, out, G);
}